// Round 1
// baseline (2466.390 us; speedup 1.0000x reference)
//
#include <hip/hip_runtime.h>
#include <cstdint>
#include <cstddef>

// Problem constants (from reference): B=4, S=2048, IN=4096, OUT=11008, GROUP=128
#define M_TOT 8192
#define N_TOT 11008
#define K_TOT 4096
#define WROW_PACK 2048   // packed int32 per W row = K/2
#define NG 32            // groups per row = K/128
#define BK 32            // K-tile (one 16x16x32 MFMA deep)
#define LDA 40           // padded LDS row length in bf16 elems (32 + 8 pad = 80 B stride)

typedef __attribute__((ext_vector_type(8))) short short8;   // bf16x8 MFMA operand (4 VGPRs)
typedef __attribute__((ext_vector_type(4))) float f32x4;    // MFMA accumulator

// (bf16(hi) << 16) | bf16(lo), truncation rounding, single v_perm_b32.
__device__ __forceinline__ unsigned int pack2_bf16(float lo, float hi) {
    return __builtin_amdgcn_perm(__float_as_uint(hi), __float_as_uint(lo), 0x07060302u);
}

// One packed byte (stored in an int32, value 0..255) -> two dequantized bf16
// weights packed in a uint. High nibble is the earlier K index (matches
// torch.stack([high, low], -1) in the reference). Exact int->float conversion
// then fma: no magic-number bias error.
__device__ __forceinline__ unsigned int dequant_pair(int q, float s, float z) {
    float wh = (float)(q >> 4) * s + z;   // q in [0,255] so >>4 gives the high nibble
    float wl = (float)(q & 15) * s + z;
    return pack2_bf16(wh, wl);            // wh at lower address (earlier k)
}

__global__ __launch_bounds__(256, 2)
void qlinear_kernel(const float* __restrict__ x,
                    const int*   __restrict__ wq,
                    const float* __restrict__ wsc,
                    const float* __restrict__ wzp,
                    float*       __restrict__ out)
{
    // 128x128 output tile per block; 4 waves in 2x2, each wave does 64x64
    // via 4x4 grid of 16x16x32 bf16 MFMAs. Single-buffered LDS, BK=32.
    __shared__ unsigned short As[128 * LDA];  // x tile,  [m][k] bf16, padded
    __shared__ unsigned short Bs[128 * LDA];  // W tile,  [n][k] bf16, padded

    const int tid  = threadIdx.x;
    const int lane = tid & 63;
    const int wv   = tid >> 6;
    const int wm   = wv >> 1;          // wave row (M)
    const int wn   = wv & 1;           // wave col (N)
    const int l15  = lane & 15;
    const int quad = lane >> 4;

    const int n0 = blockIdx.x * 128;   // N tile base
    const int m0 = blockIdx.y * 128;   // M tile base

    // ---- staging assignments (fixed per thread) ----
    // A: 128 rows x 8 float4 per row = 1024 float4; thread t handles
    //    row (i*32 + t>>3), float4 col (t&7) for i in 0..3. 8 consecutive
    //    lanes read one contiguous 128B row segment -> coalesced.
    const int ar  = tid >> 3;          // 0..31
    const int ac4 = tid & 7;           // 0..7
    // B: 128 rows x 4 int4 per row = 512 int4; thread t handles
    //    row (i*64 + t>>2), int4 col (t&3) for i in 0..1.
    const int br  = tid >> 2;          // 0..63
    const int bc  = tid & 3;           // 0..3

    const float4* a_ptrs[4];
#pragma unroll
    for (int i = 0; i < 4; ++i)
        a_ptrs[i] = reinterpret_cast<const float4*>(
                        x + (size_t)(m0 + ar + 32 * i) * K_TOT) + ac4;
    const int4* b_ptrs[2];
#pragma unroll
    for (int i = 0; i < 2; ++i)
        b_ptrs[i] = reinterpret_cast<const int4*>(
                        wq + (size_t)(n0 + br + 64 * i) * WROW_PACK) + bc;

    f32x4 acc[4][4];
#pragma unroll
    for (int i = 0; i < 4; ++i)
#pragma unroll
        for (int j = 0; j < 4; ++j)
            acc[i][j] = (f32x4)(0.0f);

    float s0 = 0.f, z0 = 0.f, s1 = 0.f, z1 = 0.f;

    for (int kt = 0; kt < K_TOT / BK; ++kt) {
        // scale/zp change only every 4 K-tiles (group size 128 = 4*BK)
        if ((kt & 3) == 0) {
            const int g = kt >> 2;
            s0 = wsc[(size_t)(n0 + br) * NG + g];
            z0 = wzp[(size_t)(n0 + br) * NG + g];
            s1 = wsc[(size_t)(n0 + br + 64) * NG + g];
            z1 = wzp[(size_t)(n0 + br + 64) * NG + g];
        }

        // ---- stage A (fp32 -> bf16) ----
#pragma unroll
        for (int i = 0; i < 4; ++i) {
            float4 v = a_ptrs[i][0];
            a_ptrs[i] += 8;  // advance 32 floats (= BK)
            unsigned int p0 = pack2_bf16(v.x, v.y);
            unsigned int p1 = pack2_bf16(v.z, v.w);
            *reinterpret_cast<uint2*>(&As[(ar + 32 * i) * LDA + ac4 * 4]) =
                make_uint2(p0, p1);
        }

        // ---- stage B (int4 nibbles -> dequant bf16) ----
#pragma unroll
        for (int i = 0; i < 2; ++i) {
            int4 q = b_ptrs[i][0];
            b_ptrs[i] += 4;  // advance 16 int32 (= BK/2 packed)
            const float s = i ? s1 : s0;
            const float z = i ? z1 : z0;
            unsigned int w01 = dequant_pair(q.x, s, z);
            unsigned int w23 = dequant_pair(q.y, s, z);
            unsigned int w45 = dequant_pair(q.z, s, z);
            unsigned int w67 = dequant_pair(q.w, s, z);
            *reinterpret_cast<uint4*>(&Bs[(br + 64 * i) * LDA + bc * 8]) =
                make_uint4(w01, w23, w45, w67);
        }

        __syncthreads();

        // ---- fragments + MFMA ----
        short8 af[4], bfr[4];
#pragma unroll
        for (int mi = 0; mi < 4; ++mi)
            af[mi] = *reinterpret_cast<const short8*>(
                &As[(wm * 64 + mi * 16 + l15) * LDA + quad * 8]);
#pragma unroll
        for (int ni = 0; ni < 4; ++ni)
            bfr[ni] = *reinterpret_cast<const short8*>(
                &Bs[(wn * 64 + ni * 16 + l15) * LDA + quad * 8]);
#pragma unroll
        for (int mi = 0; mi < 4; ++mi)
#pragma unroll
            for (int ni = 0; ni < 4; ++ni)
                acc[mi][ni] = __builtin_amdgcn_mfma_f32_16x16x32_bf16(
                    af[mi], bfr[ni], acc[mi][ni], 0, 0, 0);

        __syncthreads();
    }

    // ---- epilogue: C/D layout col=lane&15, row=quad*4+reg ----
#pragma unroll
    for (int mi = 0; mi < 4; ++mi) {
        const int row_base = m0 + wm * 64 + mi * 16 + quad * 4;
#pragma unroll
        for (int r = 0; r < 4; ++r) {
            float* dst = out + (size_t)(row_base + r) * N_TOT
                             + n0 + wn * 64 + l15;
#pragma unroll
            for (int ni = 0; ni < 4; ++ni)
                dst[ni * 16] = acc[mi][ni][r];
        }
    }
}

extern "C" void kernel_launch(void* const* d_in, const int* in_sizes, int n_in,
                              void* d_out, int out_size, void* d_ws, size_t ws_size,
                              hipStream_t stream) {
    const float* x   = (const float*)d_in[0];
    const int*   wq  = (const int*)d_in[1];
    const float* wsc = (const float*)d_in[2];
    const float* wzp = (const float*)d_in[3];
    float* out = (float*)d_out;

    dim3 grid(N_TOT / 128, M_TOT / 128);  // 86 x 64, exact (no edge tiles)
    qlinear_kernel<<<grid, dim3(256), 0, stream>>>(x, wq, wsc, wzp, out);
}